// Round 3
// baseline (130.307 us; speedup 1.0000x reference)
//
#include <hip/hip_runtime.h>
#include <stdint.h>

#define BATCH 16
#define NPIX 200704   // 448*448
#define HB 64
#define EPS 1e-6f
#define WINWORDS 16384   // 64 KB LDS window

// ---------------- constant kernel table K[j][g] = k(c_j - b_g) ----------------
__global__ void build_ktable(float* __restrict__ kt, int W) {
  int idx = blockIdx.x * 256 + threadIdx.x;
  if (idx >= W * HB) return;
  int j = idx >> 6, g = idx & 63;
  float c = ((float)j + 0.5f) / (float)W;
  float bb = (float)g / 63.0f;
  float d = (c - bb) * 50.0f;           // 1/sigma = 50
  kt[idx] = 1.0f / (1.0f + d * d);
}

// ---------------- pass 1: chroma -> fine-grid id per pixel (XCD-pinned by batch) ----------------
__global__ __launch_bounds__(256) void make_ids(const float* __restrict__ x,
                                                unsigned int* __restrict__ ids,
                                                int W, int nb) {
  int bid = blockIdx.x;
  int xcd = bid & 7;
  int t = bid >> 3;
  int c = t % nb;
  int b = xcd + 8 * (t / nb);
  int q = c * 256 + threadIdx.x;                    // uint4 index within batch
  const float4* R  = (const float4*)(x + (size_t)b * 3 * NPIX);
  const float4* G  = R + (NPIX / 4);
  const float4* Bl = G + (NPIX / 4);
  float4 rv = R[q], gv = G[q], bv = Bl[q];
  float fW = (float)W;
  float rr[4] = {rv.x, rv.y, rv.z, rv.w};
  float gg[4] = {gv.x, gv.y, gv.z, gv.w};
  float bb[4] = {bv.x, bv.y, bv.z, bv.w};
  unsigned int o[4];
#pragma unroll
  for (int t2 = 0; t2 < 4; t2++) {
    float r  = fminf(fmaxf(rr[t2], 0.0f), 1.0f);
    float g  = fminf(fmaxf(gg[t2], 0.0f), 1.0f);
    float bl = fminf(fmaxf(bb[t2], 0.0f), 1.0f);
    float inv = 1.0f / (r + g + bl + EPS);
    int i = min((int)(r * inv * fW), W - 1);
    int j = min((int)(g * inv * fW), W - 1);
    o[t2] = (unsigned int)(i * W + j);
  }
  ((uint4*)(ids + (size_t)b * NPIX))[q] = make_uint4(o[0], o[1], o[2], o[3]);
}

// ---------------- pass 2: per-(batch,window) LDS histogram, float flush ----------------
__global__ __launch_bounds__(1024) void hist_window(const unsigned int* __restrict__ ids,
                                                    float* __restrict__ Hf,
                                                    int W, int nwin) {
  __shared__ unsigned int sh[WINWORDS];
  int bid = blockIdx.x;
  int xcd = bid & 7;
  int t0 = bid >> 3;
  unsigned int w = (unsigned int)(t0 % nwin);
  int b = xcd + 8 * (t0 / nwin);
  int tid = threadIdx.x;
  for (int t = tid; t < WINWORDS; t += 1024) sh[t] = 0u;
  __syncthreads();
  const uint4* idv = (const uint4*)(ids + (size_t)b * NPIX);
  for (int t = tid; t < NPIX / 4; t += 1024) {
    uint4 v = idv[t];
    if ((v.x >> 14) == w) atomicAdd(&sh[v.x & 16383u], 1u);
    if ((v.y >> 14) == w) atomicAdd(&sh[v.y & 16383u], 1u);
    if ((v.z >> 14) == w) atomicAdd(&sh[v.z & 16383u], 1u);
    if ((v.w >> 14) == w) atomicAdd(&sh[v.w & 16383u], 1u);
  }
  __syncthreads();
  float4* dst = (float4*)(Hf + (size_t)b * W * W + (size_t)w * WINWORDS);
  for (int t = tid; t < WINWORDS / 4; t += 1024) {
    uint4 v = ((const uint4*)sh)[t];
    dst[t] = make_float4((float)v.x, (float)v.y, (float)v.z, (float)v.w);
  }
}

// ---------------- stage B: M[b][q][i][g] = sum_{j in q-slice} H[i][j] * K[j][g] ----------------
__global__ __launch_bounds__(256) void stageB(const float* __restrict__ Hf,
                                              const float* __restrict__ kt,
                                              float* __restrict__ M, int W, int Q) {
  int ntile = W >> 6;
  int bid = blockIdx.x;
  int xcd = bid & 7;
  int t0 = bid >> 3;
  int q = t0 % Q; t0 /= Q;
  int itile = t0 % ntile;
  int b = xcd + 8 * (t0 / ntile);
  __shared__ float sH[64][68];    // padded rows: 272 B, 16B-aligned, 2-way banks
  __shared__ float sK[64][64];
  int tid = threadIdx.x;
  int gq4 = (tid & 15) * 4;
  int iq4 = (tid >> 4) * 4;
  float acc[4][4];
#pragma unroll
  for (int a = 0; a < 4; a++)
#pragma unroll
    for (int c = 0; c < 4; c++) acc[a][c] = 0.0f;

  int jspan = W / Q;
  int jbase = q * jspan;
  int nch = jspan >> 6;
  const float* Hbase = Hf + ((size_t)b * W + (size_t)itile * 64) * W;

  for (int ch = 0; ch < nch; ch++) {
    int j0 = jbase + ch * 64;
#pragma unroll
    for (int rep = 0; rep < 4; rep++) {           // 1024 float4: H tile 64x64
      int idx = rep * 256 + tid;
      int ii = idx >> 4, jj4 = (idx & 15) * 4;
      float4 v = *(const float4*)&Hbase[(size_t)ii * W + (j0 + jj4)];
      *(float4*)&sH[ii][jj4] = v;
    }
#pragma unroll
    for (int rep = 0; rep < 4; rep++) {           // K tile 64x64
      int idx = rep * 256 + tid;
      int jr = idx >> 4, g4 = (idx & 15) * 4;
      *(float4*)&sK[jr][g4] = *(const float4*)&kt[(size_t)(j0 + jr) * HB + g4];
    }
    __syncthreads();
#pragma unroll 4
    for (int tt = 0; tt < 16; tt++) {             // 4 jp per step, all b128
      float hh[4][4], kk[4][4];
#pragma unroll
      for (int di = 0; di < 4; di++) {
        float4 v = *(const float4*)&sH[iq4 + di][tt * 4];
        hh[di][0] = v.x; hh[di][1] = v.y; hh[di][2] = v.z; hh[di][3] = v.w;
      }
#pragma unroll
      for (int p = 0; p < 4; p++) {
        float4 v = *(const float4*)&sK[tt * 4 + p][gq4];
        kk[p][0] = v.x; kk[p][1] = v.y; kk[p][2] = v.z; kk[p][3] = v.w;
      }
#pragma unroll
      for (int p = 0; p < 4; p++)
#pragma unroll
        for (int di = 0; di < 4; di++)
#pragma unroll
          for (int dg = 0; dg < 4; dg++)
            acc[di][dg] = fmaf(hh[di][p], kk[p][dg], acc[di][dg]);
    }
    __syncthreads();
  }

  float* Mb = M + (((size_t)b * Q + q) * W + (size_t)itile * 64) * HB;
#pragma unroll
  for (int di = 0; di < 4; di++) {
    float4 v = make_float4(acc[di][0], acc[di][1], acc[di][2], acc[di][3]);
    *(float4*)&Mb[(size_t)(iq4 + di) * HB + gq4] = v;
  }
}

// ---------------- stage C: P[b][ck][r][g] = sum_{i in 32-chunk} K[i][r] * Msum[i][g] ----------------
__global__ __launch_bounds__(256) void stageC(const float* __restrict__ M,
                                              const float* __restrict__ kt,
                                              float* __restrict__ P, int W, int Q) {
  int nck = W >> 5;                 // 32-row chunks
  int bid = blockIdx.x;
  int xcd = bid & 7;
  int t0 = bid >> 3;
  int ck = t0 % nck;
  int b = xcd + 8 * (t0 / nck);
  int i0 = ck * 32;
  __shared__ float sM[32][64];
  __shared__ float sKC[32][68];
  int tid = threadIdx.x;
  int r4 = (tid >> 4) * 4, g4 = (tid & 15) * 4;
#pragma unroll
  for (int rep = 0; rep < 8; rep++) {             // 2048 elems each
    int idx = rep * 256 + tid;
    int ii = idx >> 6, cc = idx & 63;
    float v = 0.0f;
    for (int q = 0; q < Q; q++)
      v += M[(((size_t)b * Q + q) * W + (i0 + ii)) * HB + cc];
    sM[ii][cc] = v;
    sKC[ii][cc] = kt[(size_t)(i0 + ii) * HB + cc];
  }
  __syncthreads();
  float acc[4][4];
#pragma unroll
  for (int a = 0; a < 4; a++)
#pragma unroll
    for (int c = 0; c < 4; c++) acc[a][c] = 0.0f;
#pragma unroll 8
  for (int ip = 0; ip < 32; ip++) {
    float4 kc = *(const float4*)&sKC[ip][r4];
    float4 mm = *(const float4*)&sM[ip][g4];
    float kk[4] = {kc.x, kc.y, kc.z, kc.w};
    float mv[4] = {mm.x, mm.y, mm.z, mm.w};
#pragma unroll
    for (int dr = 0; dr < 4; dr++)
#pragma unroll
      for (int dg = 0; dg < 4; dg++)
        acc[dr][dg] = fmaf(kk[dr], mv[dg], acc[dr][dg]);
  }
  float* Pb = P + ((size_t)b * nck + ck) * 4096;
#pragma unroll
  for (int dr = 0; dr < 4; dr++) {
    float4 v = make_float4(acc[dr][0], acc[dr][1], acc[dr][2], acc[dr][3]);
    *(float4*)&Pb[(size_t)(r4 + dr) * 64 + g4] = v;
  }
}

// ---------------- stage D: fixed-order reduce over chunks + normalize ----------------
__global__ __launch_bounds__(256) void stageD(const float* __restrict__ P,
                                              float* __restrict__ out, int nck) {
  int b = blockIdx.x;
  int tid = threadIdx.x;
  const float* Pb = P + (size_t)b * nck * 4096;
  float un[16];
  float psum = 0.0f;
#pragma unroll
  for (int t = 0; t < 16; t++) {
    int rg = t * 256 + tid;
    float s = 0.0f;
    for (int c = 0; c < nck; c++) s += Pb[(size_t)c * 4096 + rg];
    un[t] = s;
    psum += s;
  }
  __shared__ float red[256];
  red[tid] = psum;
  __syncthreads();
  for (int s = 128; s > 0; s >>= 1) {
    if (tid < s) red[tid] += red[tid + s];
    __syncthreads();
  }
  float inv = 1.0f / (red[0] + EPS);
#pragma unroll
  for (int t = 0; t < 16; t++) {
    out[(size_t)b * 4096 + t * 256 + tid] = un[t] * inv;
  }
}

extern "C" void kernel_launch(void* const* d_in, const int* in_sizes, int n_in,
                              void* d_out, int out_size, void* d_ws, size_t ws_size,
                              hipStream_t stream) {
  const float* x = (const float*)d_in[0];
  float* out = (float*)d_out;

  // choose fine-grid size W by available workspace (512 preferred)
  int W = 512;
  for (;;) {
    int Qtry = W >> 7; if (Qtry < 1) Qtry = 1;
    size_t need = (size_t)W * HB * 4                    // K table
                + (size_t)BATCH * W * W * 4             // H (float)
                + (size_t)BATCH * NPIX * 4              // pixel ids
                + (size_t)BATCH * Qtry * W * HB * 4     // M partials
                + (size_t)BATCH * (W >> 5) * 4096 * 4;  // P partial hists
    if (need <= ws_size || W == 128) break;
    W >>= 1;
  }
  int Q = W >> 7; if (Q < 1) Q = 1;
  int ntile = W >> 6;
  int nck = W >> 5;
  int nwin = (W * W) / WINWORDS; if (nwin < 1) nwin = 1;
  int nb = NPIX / 4 / 256;   // 196 pixel-chunks per batch in make_ids

  char* p = (char*)d_ws;
  float* kt = (float*)p;               p += (size_t)W * HB * 4;
  float* Hf = (float*)p;               p += (size_t)BATCH * W * W * 4;
  unsigned int* ids = (unsigned int*)p; p += (size_t)BATCH * NPIX * 4;
  float* M = (float*)p;                p += (size_t)BATCH * Q * W * HB * 4;
  float* P = (float*)p;

  build_ktable<<<(W * HB + 255) / 256, 256, 0, stream>>>(kt, W);
  make_ids<<<BATCH * nb, 256, 0, stream>>>(x, ids, W, nb);
  hist_window<<<BATCH * nwin, 1024, 0, stream>>>(ids, Hf, W, nwin);
  stageB<<<BATCH * ntile * Q, 256, 0, stream>>>(Hf, kt, M, W, Q);
  stageC<<<BATCH * nck, 256, 0, stream>>>(M, kt, P, W, Q);
  stageD<<<BATCH, 256, 0, stream>>>(P, out, nck);
}

// Round 4
// 76.269 us; speedup vs baseline: 1.7085x; 1.7085x over previous
//
#include <hip/hip_runtime.h>
#include <stdint.h>

#define BATCH 16
#define NPIX 200704   // 448*448
#define HB 64
#define EPS 1e-6f
#define WINWORDS 16384   // 64 KB LDS window

// ---------------- constant kernel table K[j][g] = k(c_j - b_g) ----------------
__global__ void build_ktable(float* __restrict__ kt, int W) {
  int idx = blockIdx.x * 256 + threadIdx.x;
  if (idx >= W * HB) return;
  int j = idx >> 6, g = idx & 63;
  float c = ((float)j + 0.5f) / (float)W;
  float bb = (float)g / 63.0f;
  float d = (c - bb) * 50.0f;           // 1/sigma = 50
  kt[idx] = 1.0f / (1.0f + d * d);
}

// ---------------- pass 1: chroma -> fine-grid id per pixel (XCD-pinned by batch) ----------------
__global__ __launch_bounds__(256) void make_ids(const float* __restrict__ x,
                                                unsigned int* __restrict__ ids,
                                                int W, int nb) {
  int bid = blockIdx.x;
  int xcd = bid & 7;
  int t = bid >> 3;
  int c = t % nb;
  int b = xcd + 8 * (t / nb);
  int q = c * 256 + threadIdx.x;                    // uint4 index within batch
  const float4* R  = (const float4*)(x + (size_t)b * 3 * NPIX);
  const float4* G  = R + (NPIX / 4);
  const float4* Bl = G + (NPIX / 4);
  float4 rv = R[q], gv = G[q], bv = Bl[q];
  float fW = (float)W;
  float rr[4] = {rv.x, rv.y, rv.z, rv.w};
  float gg[4] = {gv.x, gv.y, gv.z, gv.w};
  float bb[4] = {bv.x, bv.y, bv.z, bv.w};
  unsigned int o[4];
#pragma unroll
  for (int t2 = 0; t2 < 4; t2++) {
    float r  = fminf(fmaxf(rr[t2], 0.0f), 1.0f);
    float g  = fminf(fmaxf(gg[t2], 0.0f), 1.0f);
    float bl = fminf(fmaxf(bb[t2], 0.0f), 1.0f);
    float inv = 1.0f / (r + g + bl + EPS);
    int i = min((int)(r * inv * fW), W - 1);
    int j = min((int)(g * inv * fW), W - 1);
    o[t2] = (unsigned int)(i * W + j);
  }
  ((uint4*)(ids + (size_t)b * NPIX))[q] = make_uint4(o[0], o[1], o[2], o[3]);
}

// ---------------- pass 2: per-(batch,window) LDS histogram, float flush ----------------
__global__ __launch_bounds__(1024) void hist_window(const unsigned int* __restrict__ ids,
                                                    float* __restrict__ Hf,
                                                    int W, int nwin) {
  __shared__ unsigned int sh[WINWORDS];
  int bid = blockIdx.x;
  int xcd = bid & 7;
  int t0 = bid >> 3;
  unsigned int w = (unsigned int)(t0 % nwin);
  int b = xcd + 8 * (t0 / nwin);
  int tid = threadIdx.x;
  for (int t = tid; t < WINWORDS; t += 1024) sh[t] = 0u;
  __syncthreads();
  const uint4* idv = (const uint4*)(ids + (size_t)b * NPIX);
  for (int t = tid; t < NPIX / 4; t += 1024) {
    uint4 v = idv[t];
    if ((v.x >> 14) == w) atomicAdd(&sh[v.x & 16383u], 1u);
    if ((v.y >> 14) == w) atomicAdd(&sh[v.y & 16383u], 1u);
    if ((v.z >> 14) == w) atomicAdd(&sh[v.z & 16383u], 1u);
    if ((v.w >> 14) == w) atomicAdd(&sh[v.w & 16383u], 1u);
  }
  __syncthreads();
  float4* dst = (float4*)(Hf + (size_t)b * W * W + (size_t)w * WINWORDS);
  for (int t = tid; t < WINWORDS / 4; t += 1024) {
    uint4 v = ((const uint4*)sh)[t];
    dst[t] = make_float4((float)v.x, (float)v.y, (float)v.z, (float)v.w);
  }
}

// ---------------- stage B: M[b][q][i][g] = sum_{j in q-slice} H[i][j] * K[j][g] ----------------
__global__ __launch_bounds__(256) void stageB(const float* __restrict__ Hf,
                                              const float* __restrict__ kt,
                                              float* __restrict__ M, int W, int Q) {
  int ntile = W >> 6;
  int bid = blockIdx.x;
  int xcd = bid & 7;
  int t0 = bid >> 3;
  int q = t0 % Q; t0 /= Q;
  int itile = t0 % ntile;
  int b = xcd + 8 * (t0 / ntile);
  __shared__ float sH[64][68];    // padded rows: 272 B, 16B-aligned
  __shared__ float sK[64][64];
  int tid = threadIdx.x;
  int gq4 = (tid & 15) * 4;
  int iq4 = (tid >> 4) * 4;
  float acc[4][4];
#pragma unroll
  for (int a = 0; a < 4; a++)
#pragma unroll
    for (int c = 0; c < 4; c++) acc[a][c] = 0.0f;

  int jspan = W / Q;
  int jbase = q * jspan;
  int nch = jspan >> 6;
  const float* Hbase = Hf + ((size_t)b * W + (size_t)itile * 64) * W;

  for (int ch = 0; ch < nch; ch++) {
    int j0 = jbase + ch * 64;
#pragma unroll
    for (int rep = 0; rep < 4; rep++) {           // 1024 float4: H tile 64x64
      int idx = rep * 256 + tid;
      int ii = idx >> 4, jj4 = (idx & 15) * 4;
      float4 v = *(const float4*)&Hbase[(size_t)ii * W + (j0 + jj4)];
      *(float4*)&sH[ii][jj4] = v;
    }
#pragma unroll
    for (int rep = 0; rep < 4; rep++) {           // K tile 64x64
      int idx = rep * 256 + tid;
      int jr = idx >> 4, g4 = (idx & 15) * 4;
      *(float4*)&sK[jr][g4] = *(const float4*)&kt[(size_t)(j0 + jr) * HB + g4];
    }
    __syncthreads();
#pragma unroll 4
    for (int tt = 0; tt < 16; tt++) {             // 4 jp per step, all b128
      float hh[4][4], kk[4][4];
#pragma unroll
      for (int di = 0; di < 4; di++) {
        float4 v = *(const float4*)&sH[iq4 + di][tt * 4];
        hh[di][0] = v.x; hh[di][1] = v.y; hh[di][2] = v.z; hh[di][3] = v.w;
      }
#pragma unroll
      for (int p = 0; p < 4; p++) {
        float4 v = *(const float4*)&sK[tt * 4 + p][gq4];
        kk[p][0] = v.x; kk[p][1] = v.y; kk[p][2] = v.z; kk[p][3] = v.w;
      }
#pragma unroll
      for (int p = 0; p < 4; p++)
#pragma unroll
        for (int di = 0; di < 4; di++)
#pragma unroll
          for (int dg = 0; dg < 4; dg++)
            acc[di][dg] = fmaf(hh[di][p], kk[p][dg], acc[di][dg]);
    }
    __syncthreads();
  }

  float* Mb = M + (((size_t)b * Q + q) * W + (size_t)itile * 64) * HB;
#pragma unroll
  for (int di = 0; di < 4; di++) {
    float4 v = make_float4(acc[di][0], acc[di][1], acc[di][2], acc[di][3]);
    *(float4*)&Mb[(size_t)(iq4 + di) * HB + gq4] = v;
  }
}

// ---------------- stage C: P[b][ck][r][g] = sum_{i in 32-chunk} K[i][r] * Msum[i][g] ----------------
__global__ __launch_bounds__(256) void stageC(const float* __restrict__ M,
                                              const float* __restrict__ kt,
                                              float* __restrict__ P, int W, int Q) {
  int nck = W >> 5;                 // 32-row chunks
  int bid = blockIdx.x;
  int xcd = bid & 7;
  int t0 = bid >> 3;
  int ck = t0 % nck;
  int b = xcd + 8 * (t0 / nck);
  int i0 = ck * 32;
  __shared__ float sM[32][64];
  __shared__ float sKC[32][68];
  int tid = threadIdx.x;
  int r4 = (tid >> 4) * 4, g4 = (tid & 15) * 4;
#pragma unroll
  for (int rep = 0; rep < 8; rep++) {             // 2048 elems each
    int idx = rep * 256 + tid;
    int ii = idx >> 6, cc = idx & 63;
    float v = 0.0f;
    for (int q = 0; q < Q; q++)
      v += M[(((size_t)b * Q + q) * W + (i0 + ii)) * HB + cc];
    sM[ii][cc] = v;
    sKC[ii][cc] = kt[(size_t)(i0 + ii) * HB + cc];
  }
  __syncthreads();
  float acc[4][4];
#pragma unroll
  for (int a = 0; a < 4; a++)
#pragma unroll
    for (int c = 0; c < 4; c++) acc[a][c] = 0.0f;
#pragma unroll 8
  for (int ip = 0; ip < 32; ip++) {
    float4 kc = *(const float4*)&sKC[ip][r4];
    float4 mm = *(const float4*)&sM[ip][g4];
    float kk[4] = {kc.x, kc.y, kc.z, kc.w};
    float mv[4] = {mm.x, mm.y, mm.z, mm.w};
#pragma unroll
    for (int dr = 0; dr < 4; dr++)
#pragma unroll
      for (int dg = 0; dg < 4; dg++)
        acc[dr][dg] = fmaf(kk[dr], mv[dg], acc[dr][dg]);
  }
  float* Pb = P + ((size_t)b * nck + ck) * 4096;
#pragma unroll
  for (int dr = 0; dr < 4; dr++) {
    float4 v = make_float4(acc[dr][0], acc[dr][1], acc[dr][2], acc[dr][3]);
    *(float4*)&Pb[(size_t)(r4 + dr) * 64 + g4] = v;
  }
}

// ---------------- stage D1: U[b][rg] = sum_ck P[b][ck][rg]; psum[b][slice] = block sum ----------------
__global__ __launch_bounds__(256) void stageD1(const float* __restrict__ P,
                                               float* __restrict__ U,
                                               float* __restrict__ psum,
                                               int nck) {
  int bid = blockIdx.x;           // 256 blocks: xcd(3) | bh(1) | slice(4)
  int xcd = bid & 7;
  int bh = (bid >> 3) & 1;
  int slice = bid >> 4;
  int b = xcd + 8 * bh;
  int tid = threadIdx.x;
  int rg = slice * 256 + tid;
  const float* Pb = P + (size_t)b * nck * 4096;
  float s = 0.0f;
  for (int c = 0; c < nck; c++) s += Pb[(size_t)c * 4096 + rg];
  U[(size_t)b * 4096 + rg] = s;
  __shared__ float red[256];
  red[tid] = s;
  __syncthreads();
  for (int st = 128; st > 0; st >>= 1) {
    if (tid < st) red[tid] += red[tid + st];
    __syncthreads();
  }
  if (tid == 0) psum[b * 16 + slice] = red[0];
}

// ---------------- stage D2: out = U / (sum + EPS) ----------------
__global__ __launch_bounds__(256) void stageD2(const float* __restrict__ U,
                                               const float* __restrict__ psum,
                                               float* __restrict__ out) {
  int bid = blockIdx.x;           // 256 blocks: xcd(3) | bh(1) | slice(4)
  int xcd = bid & 7;
  int bh = (bid >> 3) & 1;
  int slice = bid >> 4;
  int b = xcd + 8 * bh;
  int tid = threadIdx.x;
  const float* ps = psum + b * 16;
  float tot = 0.0f;
#pragma unroll
  for (int c = 0; c < 16; c++) tot += ps[c];
  float inv = 1.0f / (tot + EPS);
  int rg = slice * 256 + tid;
  out[(size_t)b * 4096 + rg] = U[(size_t)b * 4096 + rg] * inv;
}

extern "C" void kernel_launch(void* const* d_in, const int* in_sizes, int n_in,
                              void* d_out, int out_size, void* d_ws, size_t ws_size,
                              hipStream_t stream) {
  const float* x = (const float*)d_in[0];
  float* out = (float*)d_out;

  // choose fine-grid size W by available workspace (512 preferred)
  int W = 512;
  for (;;) {
    int Qtry = W >> 7; if (Qtry < 1) Qtry = 1;
    size_t need = (size_t)W * HB * 4                    // K table
                + (size_t)BATCH * W * W * 4             // H (float)
                + (size_t)BATCH * NPIX * 4              // pixel ids
                + (size_t)BATCH * Qtry * W * HB * 4     // M partials
                + (size_t)BATCH * (W >> 5) * 4096 * 4   // P partial hists
                + (size_t)BATCH * 4096 * 4              // U unnormalized
                + (size_t)BATCH * 16 * 4;               // psum
    if (need <= ws_size || W == 128) break;
    W >>= 1;
  }
  int Q = W >> 7; if (Q < 1) Q = 1;
  int ntile = W >> 6;
  int nck = W >> 5;
  int nwin = (W * W) / WINWORDS; if (nwin < 1) nwin = 1;
  int nb = NPIX / 4 / 256;   // 196 pixel-chunks per batch in make_ids

  char* p = (char*)d_ws;
  float* kt = (float*)p;               p += (size_t)W * HB * 4;
  float* Hf = (float*)p;               p += (size_t)BATCH * W * W * 4;
  unsigned int* ids = (unsigned int*)p; p += (size_t)BATCH * NPIX * 4;
  float* M = (float*)p;                p += (size_t)BATCH * Q * W * HB * 4;
  float* P = (float*)p;                p += (size_t)BATCH * nck * 4096 * 4;
  float* U = (float*)p;                p += (size_t)BATCH * 4096 * 4;
  float* psum = (float*)p;

  build_ktable<<<(W * HB + 255) / 256, 256, 0, stream>>>(kt, W);
  make_ids<<<BATCH * nb, 256, 0, stream>>>(x, ids, W, nb);
  hist_window<<<BATCH * nwin, 1024, 0, stream>>>(ids, Hf, W, nwin);
  stageB<<<BATCH * ntile * Q, 256, 0, stream>>>(Hf, kt, M, W, Q);
  stageC<<<BATCH * nck, 256, 0, stream>>>(M, kt, P, W, Q);
  stageD1<<<256, 256, 0, stream>>>(P, U, psum, nck);
  stageD2<<<256, 256, 0, stream>>>(U, psum, out);
}

// Round 5
// 66.153 us; speedup vs baseline: 1.9698x; 1.1529x over previous
//
#include <hip/hip_runtime.h>
#include <stdint.h>

#define BATCH 16
#define NPIX 200704   // 448*448
#define HB 64
#define EPS 1e-6f
#define WINW 16384    // 64 KB LDS window (words)

// K(j,g) = 1 / (1 + ((c_j - b_g)/sigma)^2), c_j=(j+0.5)/W, b_g=g/63, 1/sigma=50
__device__ __forceinline__ float kval(int j, int g, float invW) {
  float d = (((float)j + 0.5f) * invW - (float)g * (1.0f / 63.0f)) * 50.0f;
  return 1.0f / (1.0f + d * d);
}

// ---------------- pass 1: chroma -> fine-grid id per pixel (XCD-pinned by batch) ----------------
__global__ __launch_bounds__(256) void make_ids(const float* __restrict__ x,
                                                unsigned int* __restrict__ ids,
                                                int W, int nb) {
  int bid = blockIdx.x;
  int xcd = bid & 7;
  int t = bid >> 3;
  int c = t % nb;
  int b = xcd + 8 * (t / nb);
  int q = c * 256 + threadIdx.x;                    // uint4 index within batch
  const float4* R  = (const float4*)(x + (size_t)b * 3 * NPIX);
  const float4* G  = R + (NPIX / 4);
  const float4* Bl = G + (NPIX / 4);
  float4 rv = R[q], gv = G[q], bv = Bl[q];
  float fW = (float)W;
  float rr[4] = {rv.x, rv.y, rv.z, rv.w};
  float gg[4] = {gv.x, gv.y, gv.z, gv.w};
  float bb[4] = {bv.x, bv.y, bv.z, bv.w};
  unsigned int o[4];
#pragma unroll
  for (int t2 = 0; t2 < 4; t2++) {
    float r  = fminf(fmaxf(rr[t2], 0.0f), 1.0f);
    float g  = fminf(fmaxf(gg[t2], 0.0f), 1.0f);
    float bl = fminf(fmaxf(bb[t2], 0.0f), 1.0f);
    float inv = 1.0f / (r + g + bl + EPS);
    int i = min((int)(r * inv * fW), W - 1);
    int j = min((int)(g * inv * fW), W - 1);
    o[t2] = (unsigned int)(i * W + j);
  }
  ((uint4*)(ids + (size_t)b * NPIX))[q] = make_uint4(o[0], o[1], o[2], o[3]);
}

// ---------------- pass 2: per-(batch,window) LDS histogram, float flush ----------------
__global__ __launch_bounds__(1024) void hist_window(const unsigned int* __restrict__ ids,
                                                    float* __restrict__ Hf,
                                                    int W, int nwin) {
  __shared__ unsigned int sh[WINW];
  int bid = blockIdx.x;
  int xcd = bid & 7;
  int t0 = bid >> 3;
  unsigned int w = (unsigned int)(t0 % nwin);
  int b = xcd + 8 * (t0 / nwin);
  int tid = threadIdx.x;
  for (int t = tid; t < WINW; t += 1024) sh[t] = 0u;
  __syncthreads();
  const uint4* idv = (const uint4*)(ids + (size_t)b * NPIX);
  for (int t = tid; t < NPIX / 4; t += 1024) {
    uint4 v = idv[t];
    if ((v.x >> 14) == w) atomicAdd(&sh[v.x & 16383u], 1u);
    if ((v.y >> 14) == w) atomicAdd(&sh[v.y & 16383u], 1u);
    if ((v.z >> 14) == w) atomicAdd(&sh[v.z & 16383u], 1u);
    if ((v.w >> 14) == w) atomicAdd(&sh[v.w & 16383u], 1u);
  }
  __syncthreads();
  float4* dst = (float4*)(Hf + (size_t)b * W * W + (size_t)w * WINW);
  for (int t = tid; t < WINW / 4; t += 1024) {
    uint4 v = ((const uint4*)sh)[t];
    dst[t] = make_float4((float)v.x, (float)v.y, (float)v.z, (float)v.w);
  }
}

// ---------------- stage B: M[b][q][i][g] = sum_{j in q-slice} H[i][j] * K[j][g] ----------------
__global__ __launch_bounds__(256) void stageB(const float* __restrict__ Hf,
                                              float* __restrict__ M, int W, int Q) {
  int ntile = W >> 6;
  int bid = blockIdx.x;
  int xcd = bid & 7;
  int t0 = bid >> 3;
  int q = t0 % Q; t0 /= Q;
  int itile = t0 % ntile;
  int b = xcd + 8 * (t0 / ntile);
  __shared__ float sH[64][68];    // padded rows: 272 B, 16B-aligned
  __shared__ float sK[64][64];
  int tid = threadIdx.x;
  int gq4 = (tid & 15) * 4;
  int iq4 = (tid >> 4) * 4;
  float invW = 1.0f / (float)W;
  float acc[4][4];
#pragma unroll
  for (int a = 0; a < 4; a++)
#pragma unroll
    for (int c = 0; c < 4; c++) acc[a][c] = 0.0f;

  int jspan = W / Q;            // 128
  int jbase = q * jspan;
  int nch = jspan >> 6;         // 2
  const float* Hbase = Hf + ((size_t)b * W + (size_t)itile * 64) * W;

  for (int ch = 0; ch < nch; ch++) {
    int j0 = jbase + ch * 64;
#pragma unroll
    for (int rep = 0; rep < 4; rep++) {           // 1024 float4: H tile 64x64
      int idx = rep * 256 + tid;
      int ii = idx >> 4, jj4 = (idx & 15) * 4;
      float4 v = *(const float4*)&Hbase[(size_t)ii * W + (j0 + jj4)];
      *(float4*)&sH[ii][jj4] = v;
    }
#pragma unroll
    for (int rep = 0; rep < 4; rep++) {           // K tile 64x64 computed in-place
      int idx = rep * 256 + tid;
      int jr = idx >> 4, g4 = (idx & 15) * 4;
      int jj = j0 + jr;
      sK[jr][g4 + 0] = kval(jj, g4 + 0, invW);
      sK[jr][g4 + 1] = kval(jj, g4 + 1, invW);
      sK[jr][g4 + 2] = kval(jj, g4 + 2, invW);
      sK[jr][g4 + 3] = kval(jj, g4 + 3, invW);
    }
    __syncthreads();
#pragma unroll 4
    for (int tt = 0; tt < 16; tt++) {             // 4 jp per step, all b128
      float hh[4][4], kk[4][4];
#pragma unroll
      for (int di = 0; di < 4; di++) {
        float4 v = *(const float4*)&sH[iq4 + di][tt * 4];
        hh[di][0] = v.x; hh[di][1] = v.y; hh[di][2] = v.z; hh[di][3] = v.w;
      }
#pragma unroll
      for (int p = 0; p < 4; p++) {
        float4 v = *(const float4*)&sK[tt * 4 + p][gq4];
        kk[p][0] = v.x; kk[p][1] = v.y; kk[p][2] = v.z; kk[p][3] = v.w;
      }
#pragma unroll
      for (int p = 0; p < 4; p++)
#pragma unroll
        for (int di = 0; di < 4; di++)
#pragma unroll
          for (int dg = 0; dg < 4; dg++)
            acc[di][dg] = fmaf(hh[di][p], kk[p][dg], acc[di][dg]);
    }
    __syncthreads();
  }

  float* Mb = M + (((size_t)b * Q + q) * W + (size_t)itile * 64) * HB;
#pragma unroll
  for (int di = 0; di < 4; di++) {
    float4 v = make_float4(acc[di][0], acc[di][1], acc[di][2], acc[di][3]);
    *(float4*)&Mb[(size_t)(iq4 + di) * HB + gq4] = v;
  }
}

// ---------------- stage C: P[b][ck][r][g] = sum_{i in 32-chunk} K[i][r] * Msum[i][g] ----------------
__global__ __launch_bounds__(256) void stageC(const float* __restrict__ M,
                                              float* __restrict__ P, int W, int Q) {
  int nck = W >> 5;                 // 32-row chunks
  int bid = blockIdx.x;
  int xcd = bid & 7;
  int t0 = bid >> 3;
  int ck = t0 % nck;
  int b = xcd + 8 * (t0 / nck);
  int i0 = ck * 32;
  __shared__ float sM[32][64];
  __shared__ float sKC[32][68];
  int tid = threadIdx.x;
  int r4 = (tid >> 4) * 4, g4 = (tid & 15) * 4;
  float invW = 1.0f / (float)W;
#pragma unroll
  for (int rep = 0; rep < 8; rep++) {             // 2048 elems each
    int idx = rep * 256 + tid;
    int ii = idx >> 6, cc = idx & 63;
    float v = 0.0f;
    for (int q = 0; q < Q; q++)
      v += M[(((size_t)b * Q + q) * W + (i0 + ii)) * HB + cc];
    sM[ii][cc] = v;
    sKC[ii][cc] = kval(i0 + ii, cc, invW);        // K[i][r], row=fine i, col=r bin
  }
  __syncthreads();
  float acc[4][4];
#pragma unroll
  for (int a = 0; a < 4; a++)
#pragma unroll
    for (int c = 0; c < 4; c++) acc[a][c] = 0.0f;
#pragma unroll 8
  for (int ip = 0; ip < 32; ip++) {
    float4 kc = *(const float4*)&sKC[ip][r4];
    float4 mm = *(const float4*)&sM[ip][g4];
    float kk[4] = {kc.x, kc.y, kc.z, kc.w};
    float mv[4] = {mm.x, mm.y, mm.z, mm.w};
#pragma unroll
    for (int dr = 0; dr < 4; dr++)
#pragma unroll
      for (int dg = 0; dg < 4; dg++)
        acc[dr][dg] = fmaf(kk[dr], mv[dg], acc[dr][dg]);
  }
  float* Pb = P + ((size_t)b * nck + ck) * 4096;
#pragma unroll
  for (int dr = 0; dr < 4; dr++) {
    float4 v = make_float4(acc[dr][0], acc[dr][1], acc[dr][2], acc[dr][3]);
    *(float4*)&Pb[(size_t)(r4 + dr) * 64 + g4] = v;
  }
}

// ---------------- stage D1: U[b][rg] = sum_ck P[b][ck][rg]; psum[b][slice] ----------------
__global__ __launch_bounds__(256) void stageD1(const float* __restrict__ P,
                                               float* __restrict__ U,
                                               float* __restrict__ psum,
                                               int nck) {
  int bid = blockIdx.x;           // 256 blocks: xcd(3) | bh(1) | slice(4)
  int xcd = bid & 7;
  int bh = (bid >> 3) & 1;
  int slice = bid >> 4;
  int b = xcd + 8 * bh;
  int tid = threadIdx.x;
  int rg = slice * 256 + tid;
  const float* Pb = P + (size_t)b * nck * 4096;
  float s = 0.0f;
  for (int c = 0; c < nck; c++) s += Pb[(size_t)c * 4096 + rg];
  U[(size_t)b * 4096 + rg] = s;
  __shared__ float red[256];
  red[tid] = s;
  __syncthreads();
  for (int st = 128; st > 0; st >>= 1) {
    if (tid < st) red[tid] += red[tid + st];
    __syncthreads();
  }
  if (tid == 0) psum[b * 16 + slice] = red[0];
}

// ---------------- stage D2: out = U / (sum + EPS) ----------------
__global__ __launch_bounds__(256) void stageD2(const float* __restrict__ U,
                                               const float* __restrict__ psum,
                                               float* __restrict__ out) {
  int bid = blockIdx.x;
  int xcd = bid & 7;
  int bh = (bid >> 3) & 1;
  int slice = bid >> 4;
  int b = xcd + 8 * bh;
  int tid = threadIdx.x;
  const float* ps = psum + b * 16;
  float tot = 0.0f;
#pragma unroll
  for (int c = 0; c < 16; c++) tot += ps[c];
  float inv = 1.0f / (tot + EPS);
  int rg = slice * 256 + tid;
  out[(size_t)b * 4096 + rg] = U[(size_t)b * 4096 + rg] * inv;
}

extern "C" void kernel_launch(void* const* d_in, const int* in_sizes, int n_in,
                              void* d_out, int out_size, void* d_ws, size_t ws_size,
                              hipStream_t stream) {
  const float* x = (const float*)d_in[0];
  float* out = (float*)d_out;

  // W must be a multiple of 128 (jspan=128) with W^2 a multiple of 16384.
  // Prefer 384: quantization error ~1.8x of W=512's measured 7.6e-6, stageB work x0.56.
  int W = 384;
  for (;;) {
    int Qtry = W >> 7; if (Qtry < 1) Qtry = 1;
    size_t need = (size_t)BATCH * W * W * 4             // H (float)
                + (size_t)BATCH * NPIX * 4              // pixel ids
                + (size_t)BATCH * Qtry * W * HB * 4     // M partials
                + (size_t)BATCH * (W >> 5) * 4096 * 4   // P partial hists
                + (size_t)BATCH * 4096 * 4              // U
                + (size_t)BATCH * 16 * 4;               // psum
    if (need <= ws_size || W == 128) break;
    W = (W == 384) ? 256 : 128;
  }
  int Q = W >> 7; if (Q < 1) Q = 1;
  int ntile = W >> 6;
  int nck = W >> 5;
  int nwin = (W * W) / WINW; if (nwin < 1) nwin = 1;
  int nb = NPIX / 4 / 256;   // 196 pixel-chunks per batch in make_ids

  char* p = (char*)d_ws;
  float* Hf = (float*)p;                p += (size_t)BATCH * W * W * 4;
  unsigned int* ids = (unsigned int*)p; p += (size_t)BATCH * NPIX * 4;
  float* M = (float*)p;                 p += (size_t)BATCH * Q * W * HB * 4;
  float* P = (float*)p;                 p += (size_t)BATCH * nck * 4096 * 4;
  float* U = (float*)p;                 p += (size_t)BATCH * 4096 * 4;
  float* psum = (float*)p;

  make_ids<<<BATCH * nb, 256, 0, stream>>>(x, ids, W, nb);
  hist_window<<<BATCH * nwin, 1024, 0, stream>>>(ids, Hf, W, nwin);
  stageB<<<BATCH * ntile * Q, 256, 0, stream>>>(Hf, M, W, Q);
  stageC<<<BATCH * nck, 256, 0, stream>>>(M, P, W, Q);
  stageD1<<<256, 256, 0, stream>>>(P, U, psum, nck);
  stageD2<<<256, 256, 0, stream>>>(U, psum, out);
}